// Round 3
// baseline (665.724 us; speedup 1.0000x reference)
//
#include <hip/hip_runtime.h>

typedef __attribute__((ext_vector_type(8))) short short8;
typedef __attribute__((ext_vector_type(4))) float floatx4;

#define C_DIM 50000
#define D_DIM 1024
#define N_DIM 256
#define G_NUM 4
#define NNZ_G 300000
#define E_TOT (G_NUM * NNZ_G)

// workspace layout (bytes)
#define O_SB   0u                      // scale[1024] + bias[1024] fp32 = 8192
#define O_H0   8192u                   // h0F bf16 fragment-tiled, 524288 B
#define O_ZT   532480u                 // Zt bf16 [50000][256] = 25600000
#define O_CNT  26132480u               // counts int[50000]
#define O_OFF  26332544u               // offsets int[50001]
#define O_CUR  26532608u               // cursor  int[50000]
#define O_BS   26732672u               // block sums int[256]
#define O_EDG  26733696u               // edges int2[1200000] = 9600000

static __device__ __forceinline__ unsigned short f2bf(float f) {
    union { float f; unsigned u; } v; v.f = f;
    unsigned r = v.u + 0x7fffu + ((v.u >> 16) & 1u);   // RNE
    return (unsigned short)(r >> 16);
}
static __device__ __forceinline__ float bf2f(unsigned short u) {
    union { unsigned u; float f; } v; v.u = ((unsigned)u) << 16;
    return v.f;
}

static __device__ __forceinline__ short8 cvt8(float4 a, float4 b) {
    short8 r;
    r[0] = (short)f2bf(a.x); r[1] = (short)f2bf(a.y);
    r[2] = (short)f2bf(a.z); r[3] = (short)f2bf(a.w);
    r[4] = (short)f2bf(b.x); r[5] = (short)f2bf(b.y);
    r[6] = (short)f2bf(b.z); r[7] = (short)f2bf(b.w);
    return r;
}

// ---- 1. BatchNorm stats (32 blocks x 256: 8 n-groups x 32 d-cols each)
__global__ __launch_bounds__(256) void k_bnstats(const float* __restrict__ x,
                                                 float* __restrict__ scale,
                                                 float* __restrict__ bias) {
    __shared__ float sms[8][32], smss[8][32];
    const int t = threadIdx.x;
    const int dc = t & 31, grp = t >> 5;
    const int d = blockIdx.x * 32 + dc;
    float s = 0.f, ss = 0.f;
    for (int n = grp; n < N_DIM; n += 8) {
        float v = x[n * D_DIM + d];
        s += v; ss += v * v;
    }
    sms[grp][dc] = s; smss[grp][dc] = ss;
    __syncthreads();
    if (t < 32) {
        float S = 0.f, SS = 0.f;
#pragma unroll
        for (int g2 = 0; g2 < 8; ++g2) { S += sms[g2][t]; SS += smss[g2][t]; }
        float mean = S * (1.f / N_DIM);
        float var  = SS * (1.f / N_DIM) - mean * mean;
        float sc = rsqrtf(var + 1e-5f);
        int dd = blockIdx.x * 32 + t;
        scale[dd] = sc;
        bias[dd] = -mean * sc;
    }
}

// ---- 2. h0F = normalize(x), bf16, MFMA-B-fragment-tiled layout.
// chunk (b, kc) = 8 bf16 of h0[b][kc*8 .. +8] stored at ushort offset
//   (b>>4)*16384 + (kc>>2)*512 + (kc&3)*128 + (b&15)*8
// so a wave's B-frag load (n-group, kstep) is contiguous 1024 B: base + lane*16B.
__global__ __launch_bounds__(256) void k_h0f(const float* __restrict__ x,
                                             const float* __restrict__ scale,
                                             const float* __restrict__ bias,
                                             unsigned short* __restrict__ h0F) {
    int id = blockIdx.x * 256 + threadIdx.x;        // 32768 chunks
    int b = id >> 7, kc = id & 127;
    const float4* xp = (const float4*)&x[(size_t)b * D_DIM + kc * 8];
    float4 f0 = xp[0], f1 = xp[1];
    const float4* sp = (const float4*)&scale[kc * 8];
    const float4* bp = (const float4*)&bias[kc * 8];
    float4 s0 = sp[0], s1 = sp[1], b0 = bp[0], b1 = bp[1];
    short8 o;
    o[0] = (short)f2bf(f0.x * s0.x + b0.x);
    o[1] = (short)f2bf(f0.y * s0.y + b0.y);
    o[2] = (short)f2bf(f0.z * s0.z + b0.z);
    o[3] = (short)f2bf(f0.w * s0.w + b0.w);
    o[4] = (short)f2bf(f1.x * s1.x + b1.x);
    o[5] = (short)f2bf(f1.y * s1.y + b1.y);
    o[6] = (short)f2bf(f1.z * s1.z + b1.z);
    o[7] = (short)f2bf(f1.w * s1.w + b1.w);
    int off = (b >> 4) * 16384 + (kc >> 2) * 512 + (kc & 3) * 128 + (b & 15) * 8;
    *(short8*)&h0F[off] = o;
}

// ---- 3. GEMM: Zt[c][b] = swish(W@h0 + wb).
// Wave-independent: NO LDS, NO barriers. Block = 4 waves over a 64C x 256N
// region; wave (w&1) picks C-half (+0/+32), (w>>1) picks N-half (+0/+128).
// Each wave: 32C x 128N output, acc[2][8]. A straight from W (fp32->bf16 in
// regs); B straight from h0F (contiguous 1KB wave loads, L2-hot). 1-step
// software pipeline with two named register sets; waves free-run, latency
// hidden by ILP + TLP. W rows read by the 2 N-half waves of the same block
// (same CU -> L1/L2 reuse), HBM traffic unchanged.
__global__ __launch_bounds__(256) void k_gemm(const float* __restrict__ W,
                                              const float* __restrict__ wb,
                                              const unsigned short* __restrict__ h0F,
                                              unsigned short* __restrict__ Zt) {
    const int t = threadIdx.x;
    const int w = t >> 6, lane = t & 63;
    const int m = lane & 15, g = lane >> 4;
    const int cb = blockIdx.x * 64 + (w & 1) * 32;   // this wave's 32 C-rows
    const int nh = w >> 1;                           // this wave's N-half

    int ra0 = cb + m;      if (ra0 >= C_DIM) ra0 = C_DIM - 1;
    int ra1 = cb + 16 + m; if (ra1 >= C_DIM) ra1 = C_DIM - 1;
    const float* pA0 = &W[(size_t)ra0 * D_DIM + g * 8];
    const float* pA1 = &W[(size_t)ra1 * D_DIM + g * 8];
    const unsigned short* hb = h0F + (size_t)(nh * 8) * 16384 + lane * 8;

    floatx4 acc[2][8];
#pragma unroll
    for (int i = 0; i < 2; ++i)
#pragma unroll
        for (int j = 0; j < 8; ++j) acc[i][j] = (floatx4)0.f;

#define LOADN(A0L, A0H, A1L, A1H, NB, ksv)                                    \
    {                                                                         \
        const int kkv = (ksv) * 32;                                           \
        A0L = *(const float4*)(pA0 + kkv);                                    \
        A0H = *(const float4*)(pA0 + kkv + 4);                                \
        A1L = *(const float4*)(pA1 + kkv);                                    \
        A1H = *(const float4*)(pA1 + kkv + 4);                                \
        _Pragma("unroll")                                                     \
        for (int j = 0; j < 8; ++j)                                           \
            NB[j] = *(const short8*)&hb[(size_t)j * 16384 + (ksv) * 512];     \
    }

// one K=32 step: prefetch (ksv+1) into the "next" set, convert+MFMA "cur" set
#define STEP(A0L, A0H, A1L, A1H, CB, nA0L, nA0H, nA1L, nA1H, NB, ksv)         \
    {                                                                         \
        if ((ksv) < 31) LOADN(nA0L, nA0H, nA1L, nA1H, NB, (ksv) + 1)          \
        short8 af0 = cvt8(A0L, A0H);                                          \
        short8 af1 = cvt8(A1L, A1H);                                          \
        _Pragma("unroll")                                                     \
        for (int j = 0; j < 8; ++j) {                                         \
            acc[0][j] = __builtin_amdgcn_mfma_f32_16x16x32_bf16(              \
                af0, CB[j], acc[0][j], 0, 0, 0);                              \
            acc[1][j] = __builtin_amdgcn_mfma_f32_16x16x32_bf16(              \
                af1, CB[j], acc[1][j], 0, 0, 0);                              \
        }                                                                     \
    }

    float4 xa0, xa1, xa2, xa3, ya0, ya1, ya2, ya3;
    short8 xb[8], yb[8];

    LOADN(xa0, xa1, xa2, xa3, xb, 0)
#pragma unroll 1
    for (int ks2 = 0; ks2 < 32; ks2 += 2) {
        STEP(xa0, xa1, xa2, xa3, xb, ya0, ya1, ya2, ya3, yb, ks2)
        STEP(ya0, ya1, ya2, ya3, yb, xa0, xa1, xa2, xa3, xb, ks2 + 1)
    }
#undef STEP
#undef LOADN

    // epilogue: bias + swish, store bf16 to Zt[c][b]
#pragma unroll
    for (int i = 0; i < 2; ++i) {
#pragma unroll
        for (int j = 0; j < 8; ++j) {
            int b = nh * 128 + j * 16 + m;
#pragma unroll
            for (int rr = 0; rr < 4; ++rr) {
                int c = cb + i * 16 + g * 4 + rr;
                if (c < C_DIM) {
                    float x = acc[i][j][rr] + wb[c];
                    float z = x / (1.f + __expf(-x));
                    Zt[(size_t)c * 256 + b] = f2bf(z);
                }
            }
        }
    }
}

// ---- 4. CSR build
__global__ __launch_bounds__(256) void k_count(const int* __restrict__ rows,
                                               int* __restrict__ counts) {
    int id = blockIdx.x * 256 + threadIdx.x;
    if (id < E_TOT) atomicAdd(&counts[rows[id]], 1);
}

__global__ __launch_bounds__(256) void k_scan1(const int* __restrict__ counts,
                                               int* __restrict__ offsets,
                                               int* __restrict__ bsums) {
    __shared__ int sm[256];
    int t = threadIdx.x, i = blockIdx.x * 256 + t;
    int v = (i < C_DIM) ? counts[i] : 0;
    sm[t] = v; __syncthreads();
    for (int off = 1; off < 256; off <<= 1) {
        int x = (t >= off) ? sm[t - off] : 0;
        __syncthreads();
        sm[t] += x;
        __syncthreads();
    }
    if (i < C_DIM) offsets[i] = sm[t] - v;
    if (t == 255) bsums[blockIdx.x] = sm[255];
}

__global__ __launch_bounds__(256) void k_scan2(int* __restrict__ bsums,
                                               int* __restrict__ offsets) {
    __shared__ int sm[256];
    int t = threadIdx.x;
    int v = (t < 196) ? bsums[t] : 0;
    sm[t] = v; __syncthreads();
    for (int off = 1; off < 256; off <<= 1) {
        int x = (t >= off) ? sm[t - off] : 0;
        __syncthreads();
        sm[t] += x;
        __syncthreads();
    }
    if (t < 196) bsums[t] = sm[t] - v;
    if (t == 0) offsets[C_DIM] = sm[255];
}

__global__ __launch_bounds__(256) void k_scan3(const int* __restrict__ bsums,
                                               int* __restrict__ offsets,
                                               int* __restrict__ cursor) {
    int i = blockIdx.x * 256 + threadIdx.x;
    if (i < C_DIM) {
        int off = offsets[i] + bsums[blockIdx.x];
        offsets[i] = off;
        cursor[i] = off;
    }
}

__global__ __launch_bounds__(256) void k_scatter(const int* __restrict__ rows,
                                                 const int* __restrict__ cols,
                                                 const float* __restrict__ vals,
                                                 const float* __restrict__ vec,
                                                 int* __restrict__ cursor,
                                                 int2* __restrict__ edges) {
    int id = blockIdx.x * 256 + threadIdx.x;
    if (id < E_TOT) {
        int gidx = id / NNZ_G;
        float v = vals[id] * vec[gidx];
        int r = rows[id];
        int c = cols[id];
        int pos = atomicAdd(&cursor[r], 1);
        edges[pos] = make_int2(c, __float_as_int(v));
    }
}

// ---- 5. Aggregation + residual. Block = 4 waves = 32 rows (wave: 8 rows seq).
// 2 edges per wave instruction (32 lanes x 16B each), 4 edges in flight,
// cross-half combine via shfl_xor(32).
__global__ __launch_bounds__(256) void k_agg(const unsigned short* __restrict__ Zt,
                                             const int* __restrict__ offsets,
                                             const int2* __restrict__ edges,
                                             float* __restrict__ out) {
    __shared__ float sm[32 * 256];
    const int t = threadIdx.x;
    const int w = t >> 6, lane = t & 63;
    const int r0 = blockIdx.x * 32;
    const int h = lane & 31;          // col chunk: cols [h*8, h*8+8)
    const int eh = lane >> 5;         // which edge of the pair
    const int base = h * 8;

#pragma unroll 1
    for (int k = 0; k < 8; ++k) {
        int lrow = w * 8 + k;
        int r = __builtin_amdgcn_readfirstlane(r0 + lrow);
        if (r < C_DIM) {
            float a[8];
            {   // residual Z: only half 0 contributes (half 1 added via combine)
                short8 z = *(const short8*)&Zt[(size_t)r * 256 + base];
                float zm = eh ? 0.f : 1.f;
#pragma unroll
                for (int j = 0; j < 8; ++j) a[j] = zm * bf2f((unsigned short)z[j]);
            }
            int s = offsets[r], e = offsets[r + 1];
            for (; s + 4 <= e; s += 4) {
                int2 ea = edges[s + eh];
                int2 eb = edges[s + 2 + eh];
                short8 ga = *(const short8*)&Zt[(size_t)(unsigned)ea.x * 256 + base];
                short8 gb = *(const short8*)&Zt[(size_t)(unsigned)eb.x * 256 + base];
                float va = __int_as_float(ea.y), vb = __int_as_float(eb.y);
#pragma unroll
                for (int j = 0; j < 8; ++j)
                    a[j] += va * bf2f((unsigned short)ga[j]) + vb * bf2f((unsigned short)gb[j]);
            }
            for (; s + 2 <= e; s += 2) {
                int2 ea = edges[s + eh];
                short8 ga = *(const short8*)&Zt[(size_t)(unsigned)ea.x * 256 + base];
                float va = __int_as_float(ea.y);
#pragma unroll
                for (int j = 0; j < 8; ++j)
                    a[j] += va * bf2f((unsigned short)ga[j]);
            }
            if (s < e) {   // single tail edge: half 1 contributes 0
                int2 e0 = edges[s];
                short8 g0 = *(const short8*)&Zt[(size_t)(unsigned)e0.x * 256 + base];
                float v0 = eh ? 0.f : __int_as_float(e0.y);
#pragma unroll
                for (int j = 0; j < 8; ++j)
                    a[j] += v0 * bf2f((unsigned short)g0[j]);
            }
#pragma unroll
            for (int j = 0; j < 8; ++j) a[j] += __shfl_xor(a[j], 32);
            if (eh == 0) {
                *(float4*)&sm[lrow * 256 + base]     = make_float4(a[0], a[1], a[2], a[3]);
                *(float4*)&sm[lrow * 256 + base + 4] = make_float4(a[4], a[5], a[6], a[7]);
            }
        }
    }
    __syncthreads();

    int rows = C_DIM - r0; if (rows > 32) rows = 32;
    int nq = rows >> 2;
    float4* op = (float4*)&out[(size_t)t * C_DIM + r0];
#pragma unroll 1
    for (int q = 0; q < nq; ++q) {
        float4 o;
        o.x = sm[(q * 4 + 0) * 256 + t];
        o.y = sm[(q * 4 + 1) * 256 + t];
        o.z = sm[(q * 4 + 2) * 256 + t];
        o.w = sm[(q * 4 + 3) * 256 + t];
        op[q] = o;
    }
}

extern "C" void kernel_launch(void* const* d_in, const int* in_sizes, int n_in,
                              void* d_out, int out_size, void* d_ws, size_t ws_size,
                              hipStream_t stream) {
    (void)in_sizes; (void)n_in; (void)out_size; (void)ws_size;
    const float* x     = (const float*)d_in[0];
    const float* W     = (const float*)d_in[1];
    const float* wb    = (const float*)d_in[2];
    const float* Avals = (const float*)d_in[3];
    const float* vec   = (const float*)d_in[4];
    const int*   Arows = (const int*)d_in[5];
    const int*   Acols = (const int*)d_in[6];
    float* out = (float*)d_out;
    char* ws = (char*)d_ws;

    float* scale = (float*)(ws + O_SB);
    float* bias  = scale + 1024;
    unsigned short* h0F = (unsigned short*)(ws + O_H0);
    unsigned short* Zt  = (unsigned short*)(ws + O_ZT);
    int* counts  = (int*)(ws + O_CNT);
    int* offsets = (int*)(ws + O_OFF);
    int* cursor  = (int*)(ws + O_CUR);
    int* bsums   = (int*)(ws + O_BS);
    int2* edges  = (int2*)(ws + O_EDG);

    hipMemsetAsync(counts, 0, C_DIM * sizeof(int), stream);

    k_bnstats<<<32, 256, 0, stream>>>(x, scale, bias);
    k_h0f<<<128, 256, 0, stream>>>(x, scale, bias, h0F);
    k_count<<<(E_TOT + 255) / 256, 256, 0, stream>>>(Arows, counts);
    k_gemm<<<(C_DIM + 63) / 64, 256, 0, stream>>>(W, wb, h0F, Zt);
    k_scan1<<<196, 256, 0, stream>>>(counts, offsets, bsums);
    k_scan2<<<1, 256, 0, stream>>>(bsums, offsets);
    k_scan3<<<196, 256, 0, stream>>>(bsums, offsets, cursor);
    k_scatter<<<(E_TOT + 255) / 256, 256, 0, stream>>>(Arows, Acols, Avals, vec, cursor, edges);
    k_agg<<<(C_DIM + 31) / 32, 256, 0, stream>>>(Zt, offsets, edges, out);
}